// Round 6
// baseline (561.629 us; speedup 1.0000x reference)
//
#include <hip/hip_runtime.h>
#include <math.h>

#define BATCH 32768
#define SEQLEN 200
#define PSTEPS 50
#define HID 32
#define LDS_PAD 36   // float row stride 36 -> mild bank aliasing only (m136)

typedef __attribute__((ext_vector_type(2))) _Float16 half2v;
typedef __attribute__((ext_vector_type(8))) _Float16 half8v;
typedef __attribute__((ext_vector_type(2))) __fp16   fp16x2;   // cvt_pkrtz return type
typedef __attribute__((ext_vector_type(4))) float floatx4;
typedef __attribute__((ext_vector_type(2))) float float2v;

#define RCPF __builtin_amdgcn_rcpf       // v_rcp_f32
#define PKRTZ __builtin_amdgcn_cvt_pkrtz // v_cvt_pkrtz_f16_f32

union H8 { unsigned int u[4]; half8v h; half2v h2[4]; };
union HU { fp16x2 h; unsigned int u; };

__device__ __forceinline__ unsigned int pk(float a, float b) {
    HU t; t.h = PKRTZ(a, b); return t.u;
}

__device__ __forceinline__ float2v v2(float a, float b) { return (float2v){a, b}; }
__device__ __forceinline__ float2v pfma(float2v a, float2v b, float2v c) {
    return __builtin_elementwise_fma(a, b, c);    // -> v_pk_fma_f32
}

// Depth-6 CF Pade of tanh: x*p(t)/q(t), t=x^2, input clamped to [-4,4] (med3).
// err <= 1.5e-5 inside, <= 6.7e-4 saturation err at clamp. Returns numerator
// x*p; q returned by ref so callers can share one rcp across several tanhs
// (all q > 0).
__device__ __forceinline__ float2v tanh_pq(float2v x, float2v& q) {
    float2v xc;
    xc.x = fminf(fmaxf(x.x, -4.0f), 4.0f);        // v_med3_f32 (inline consts)
    xc.y = fminf(fmaxf(x.y, -4.0f), 4.0f);
    const float2v t = xc * xc;
    float2v p = t + v2(378.f, 378.f);
    p = pfma(p, t, v2(17325.f, 17325.f));
    p = pfma(p, t, v2(135135.f, 135135.f));
    float2v qq = pfma(t, v2(28.f, 28.f), v2(3150.f, 3150.f));
    qq = pfma(qq, t, v2(62370.f, 62370.f));
    q = pfma(qq, t, v2(135135.f, 135135.f));
    return xc * p;
}

// One GROUP = 16 batch elements = one 128-thread block = 2 waves (R5 split).
// Gates i,f,o weight rows pre-scaled by 0.5 (sigma(x)=0.5+0.5*tanh(x/2)), so
// MFMA outputs are tanh arguments directly. No exp anywhere: 2 rcp per cell.
// C layout: row(batch)=quad*4+reg, col(gate)=lane&15; A: m=lane&15, k=quad*8+j.
__global__ __launch_bounds__(128, 4)
void lstm_mfma_kernel(const float* __restrict__ hist, const float* __restrict__ W_ih,
                      const float* __restrict__ W_hh, const float* __restrict__ b_ih,
                      const float* __restrict__ b_hh, const float* __restrict__ W_pred,
                      const float* __restrict__ b_pred, float* __restrict__ out)
{
    const int lane = threadIdx.x & 63;
    const int half = threadIdx.x >> 6;        // 0 or 1: which 16 hidden units
    const int m    = lane & 15;
    const int quad = lane >> 4;
    const int elem0 = blockIdx.x * 16;
    const int u    = half * 16 + m;           // this lane's hidden-unit column

    __shared__ __align__(16) float hbuf[2][16][LDS_PAD];   // ping-pong h state

    // ---- resident weight fragments (f16; this wave's 4 gate tiles) ----
    // gate order g=0..3 -> i,f,g,o ; scale 0.5 for i,f,o (sigma arg), 1 for g
    const float gsc[4] = { 0.5f, 0.5f, 1.0f, 0.5f };
    half8v Bh[4], B2[4];
    #pragma unroll
    for (int g = 0; g < 4; ++g) {
        const int gc = g * 32 + u;            // gate row for this unit
        const float sc = gsc[g];
        H8 bh;
        #pragma unroll
        for (int jj = 0; jj < 4; ++jj) {
            bh.h2[jj] = (half2v){ (_Float16)(sc * W_hh[gc * HID + quad * 8 + 2 * jj]),
                                  (_Float16)(sc * W_hh[gc * HID + quad * 8 + 2 * jj + 1]) };
        }
        Bh[g] = bh.h;
        H8 b2; b2.u[0] = b2.u[1] = b2.u[2] = b2.u[3] = 0u;
        if (quad == 0) {
            b2.h2[0] = (half2v){ (_Float16)(sc * W_ih[gc * 4 + 0]), (_Float16)(sc * W_ih[gc * 4 + 1]) };
            b2.h2[1] = (half2v){ (_Float16)(sc * W_ih[gc * 4 + 2]), (_Float16)(sc * W_ih[gc * 4 + 3]) };
            float bsum = sc * (b_ih[gc] + b_hh[gc]);
            _Float16 bhi = (_Float16)bsum;
            _Float16 blo = (_Float16)(bsum - (float)bhi);   // bias exact to ~2^-24
            b2.h2[2] = (half2v){ bhi, blo };                // K rows 4,5 (A = 1,1)
        }
        B2[g] = b2.h;
    }
    const unsigned int one2 = 0x3C003C00u;     // (1.0h, 1.0h)
    const float2v halfc = v2(0.5f, 0.5f);

    // ---- init h=0 in buf0, c=0 in regs ----
    float cst[4];
    #pragma unroll
    for (int r = 0; r < 4; ++r) { cst[r] = 0.f; hbuf[0][quad * 4 + r][u] = 0.f; }
    asm volatile("s_waitcnt lgkmcnt(0)" ::: "memory");
    __builtin_amdgcn_s_barrier();

    // ---- encode: 200 steps ----
    const float4* xp = (const float4*)(hist + (size_t)(elem0 + m) * (SEQLEN * 4));
    float4 xv = xp[0];
    #pragma unroll 1
    for (int t = 0; t < SEQLEN; ++t) {
        const int rd = t & 1;
        float4 h0 = *(const float4*)&hbuf[rd][m][quad * 8];
        float4 h1 = *(const float4*)&hbuf[rd][m][quad * 8 + 4];
        H8 ahu;
        ahu.u[0] = pk(h0.x, h0.y); ahu.u[1] = pk(h0.z, h0.w);
        ahu.u[2] = pk(h1.x, h1.y); ahu.u[3] = pk(h1.z, h1.w);
        const half8v ah = ahu.h;

        const unsigned int tx0 = pk(xv.x, xv.y), tx1 = pk(xv.z, xv.w);
        H8 a2u;
        a2u.u[0] = (quad == 0) ? tx0 : 0u;
        a2u.u[1] = (quad == 0) ? tx1 : 0u;
        a2u.u[2] = (quad == 0) ? one2 : 0u;
        a2u.u[3] = 0u;
        const half8v a2 = a2u.h;

        const int tn = (t + 1 < SEQLEN) ? t + 1 : SEQLEN - 1;
        float4 xn = xp[tn];                    // prefetch stays in flight

        floatx4 acc[4];                        // tanh-args: i/2, f/2, g, o/2
        #pragma unroll
        for (int g = 0; g < 4; ++g) {
            floatx4 a = __builtin_amdgcn_mfma_f32_16x16x32_f16(a2, B2[g], (floatx4){0.f,0.f,0.f,0.f}, 0, 0, 0);
            acc[g] = __builtin_amdgcn_mfma_f32_16x16x32_f16(ah, Bh[g], a, 0, 0, 0);
        }
        #pragma unroll
        for (int pr = 0; pr < 2; ++pr) {
            const int r0 = pr * 2;
            float2v gi = v2(acc[0][r0], acc[0][r0 + 1]);
            float2v gf = v2(acc[1][r0], acc[1][r0 + 1]);
            float2v gg = v2(acc[2][r0], acc[2][r0 + 1]);
            float2v go = v2(acc[3][r0], acc[3][r0 + 1]);
            float2v cc = v2(cst[r0], cst[r0 + 1]);

            float2v qi, qf, qg;
            float2v ni = tanh_pq(gi, qi);
            float2v nf = tanh_pq(gf, qf);
            float2v ng = tanh_pq(gg, qg);
            float2v q2 = qi * qf;
            float2v Q  = q2 * qg;
            float2v R  = v2(RCPF(Q.x), RCPF(Q.y));
            float2v Tg = ng * (R * q2);
            float2v Tf = nf * (R * (qi * qg));
            float2v Ti = ni * (R * (qf * qg));
            float2v si = pfma(Ti, halfc, halfc);
            float2v sf = pfma(Tf, halfc, halfc);
            float2v cn = pfma(sf, cc, si * Tg);

            float2v qo, qc;
            float2v no = tanh_pq(go, qo);
            float2v nc = tanh_pq(cn, qc);
            float2v Q2 = qo * qc;
            float2v R2 = v2(RCPF(Q2.x), RCPF(Q2.y));
            float2v To = no * (R2 * qc);
            float2v Tc = nc * (R2 * qo);
            float2v so = pfma(To, halfc, halfc);
            float2v hn = so * Tc;

            cst[r0] = cn.x; cst[r0 + 1] = cn.y;
            hbuf[rd ^ 1][quad * 4 + r0][u]     = hn.x;
            hbuf[rd ^ 1][quad * 4 + r0 + 1][u] = hn.y;
        }
        asm volatile("s_waitcnt lgkmcnt(0)" ::: "memory");
        __builtin_amdgcn_s_barrier();
        xv = xn;
    }

    // ---- decode: 50 steps (c reset to 0 -> f-gate dead) ----
    float wp[4][8];
    #pragma unroll
    for (int d = 0; d < 4; ++d)
        #pragma unroll
        for (int j = 0; j < 8; ++j) wp[d][j] = W_pred[d * HID + quad * 8 + j];
    float bp[4] = { b_pred[0], b_pred[1], b_pred[2], b_pred[3] };

    float* op = out + (size_t)(elem0 + m) * (PSTEPS * 4);
    #pragma unroll 1
    for (int p = 0; p < PSTEPS; ++p) {
        const int rd = p & 1;                  // encode ended with h in buf0
        float4 h0 = *(const float4*)&hbuf[rd][m][quad * 8];
        float4 h1 = *(const float4*)&hbuf[rd][m][quad * 8 + 4];
        const float hv[8] = { h0.x, h0.y, h0.z, h0.w, h1.x, h1.y, h1.z, h1.w };

        float pd[4];
        #pragma unroll
        for (int d = 0; d < 4; ++d) {
            float s = 0.f;
            #pragma unroll
            for (int j = 0; j < 8; ++j) s = fmaf(hv[j], wp[d][j], s);
            s += __shfl_xor(s, 16);
            s += __shfl_xor(s, 32);
            pd[d] = s + bp[d];
        }
        if (half == 0 && quad == 0) *(float4*)(op + p * 4) = make_float4(pd[0], pd[1], pd[2], pd[3]);

        if (p + 1 < PSTEPS) {
            H8 ahu;
            ahu.u[0] = pk(hv[0], hv[1]); ahu.u[1] = pk(hv[2], hv[3]);
            ahu.u[2] = pk(hv[4], hv[5]); ahu.u[3] = pk(hv[6], hv[7]);
            const half8v ah = ahu.h;
            const unsigned int tx0 = pk(pd[0], pd[1]), tx1 = pk(pd[2], pd[3]);
            H8 a2u;
            a2u.u[0] = (quad == 0) ? tx0 : 0u;
            a2u.u[1] = (quad == 0) ? tx1 : 0u;
            a2u.u[2] = (quad == 0) ? one2 : 0u;
            a2u.u[3] = 0u;
            const half8v a2 = a2u.h;

            floatx4 acc[3];                    // gates i,g,o (f dead: c==0)
            #pragma unroll
            for (int k = 0; k < 3; ++k) {
                const int g = (k == 0) ? 0 : k + 1;   // tiles 0,2,3 = i,g,o
                floatx4 a = __builtin_amdgcn_mfma_f32_16x16x32_f16(a2, B2[g], (floatx4){0.f,0.f,0.f,0.f}, 0, 0, 0);
                acc[k] = __builtin_amdgcn_mfma_f32_16x16x32_f16(ah, Bh[g], a, 0, 0, 0);
            }
            #pragma unroll
            for (int pr = 0; pr < 2; ++pr) {
                const int r0 = pr * 2;
                float2v gi = v2(acc[0][r0], acc[0][r0 + 1]);
                float2v gg = v2(acc[1][r0], acc[1][r0 + 1]);
                float2v go = v2(acc[2][r0], acc[2][r0 + 1]);

                float2v qi, qg;
                float2v ni = tanh_pq(gi, qi);
                float2v ng = tanh_pq(gg, qg);
                float2v Q  = qi * qg;
                float2v R  = v2(RCPF(Q.x), RCPF(Q.y));
                float2v Ti = ni * (R * qg);
                float2v Tg = ng * (R * qi);
                float2v si = pfma(Ti, halfc, halfc);
                float2v cn = si * Tg;          // |cn| < 1

                float2v qo, qc;
                float2v no = tanh_pq(go, qo);
                float2v nc = tanh_pq(cn, qc);
                float2v Q2 = qo * qc;
                float2v R2 = v2(RCPF(Q2.x), RCPF(Q2.y));
                float2v To = no * (R2 * qc);
                float2v Tc = nc * (R2 * qo);
                float2v so = pfma(To, halfc, halfc);
                float2v hn = so * Tc;

                hbuf[rd ^ 1][quad * 4 + r0][u]     = hn.x;
                hbuf[rd ^ 1][quad * 4 + r0 + 1][u] = hn.y;
            }
            asm volatile("s_waitcnt lgkmcnt(0)" ::: "memory");
            __builtin_amdgcn_s_barrier();
        }
    }
}

extern "C" void kernel_launch(void* const* d_in, const int* in_sizes, int n_in,
                              void* d_out, int out_size, void* d_ws, size_t ws_size,
                              hipStream_t stream) {
    const float* hist   = (const float*)d_in[0];
    const float* W_ih   = (const float*)d_in[1];
    const float* W_hh   = (const float*)d_in[2];
    const float* b_ih   = (const float*)d_in[3];
    const float* b_hh   = (const float*)d_in[4];
    const float* W_pred = (const float*)d_in[5];
    const float* b_pred = (const float*)d_in[6];
    float* out = (float*)d_out;

    const int blocks = BATCH / 16;   // 2048 blocks x 128 thr = 4096 waves = 4/SIMD
    lstm_mfma_kernel<<<blocks, 128, 0, stream>>>(hist, W_ih, W_hh, b_ih, b_hh,
                                                 W_pred, b_pred, out);
}

// Round 8
// 495.101 us; speedup vs baseline: 1.1344x; 1.1344x over previous
//
#include <hip/hip_runtime.h>
#include <math.h>

#define BATCH 32768
#define SEQLEN 200
#define PSTEPS 50
#define HID 32
#define LDS_PAD 36   // float row stride 36 -> mild bank aliasing only (m136)

typedef __attribute__((ext_vector_type(2))) _Float16 half2v;
typedef __attribute__((ext_vector_type(8))) _Float16 half8v;
typedef __attribute__((ext_vector_type(2))) __fp16   fp16x2;   // cvt_pkrtz return type
typedef __attribute__((ext_vector_type(4))) float floatx4;
typedef __attribute__((ext_vector_type(2))) float float2v;

#define RCPF __builtin_amdgcn_rcpf       // v_rcp_f32
#define PKRTZ __builtin_amdgcn_cvt_pkrtz // v_cvt_pkrtz_f16_f32

union H8 { unsigned int u[4]; half8v h; half2v h2[4]; };
union HU { fp16x2 h; unsigned int u; };
union ACC { floatx4 f4; float2v f2[2]; };   // even-aligned sub-pair views (free extracts)

__device__ __forceinline__ unsigned int pk(float a, float b) {
    HU t; t.h = PKRTZ(a, b); return t.u;
}
__device__ __forceinline__ float2v pfma(float2v a, float2v b, float2v c) {
    return __builtin_elementwise_fma(a, b, c);   // v2f32 fma -> v_pk_fma_f32 (gfx90a+)
}
__device__ __forceinline__ float2v rcp2(float2v d) {
    return (float2v){ RCPF(d.x), RCPF(d.y) };    // rcp has no packed form
}

// tanh(x) ~= x*p(t)/q(t), t=x^2 (CF(3,3): err <=1.5e-5 on [-4,4], sat err
// 6.7e-4 at clamp — R6 end-to-end absmax identical to exp path). q >= 135135
// always; callers cross-multiply denominators to share rcps.
__device__ __forceinline__ float2v tanh_pq(float2v x, float2v& q) {
    const float2v c4 = {4.f, 4.f}, cm4 = {-4.f, -4.f};
    float2v xc = __builtin_elementwise_min(__builtin_elementwise_max(x, cm4), c4);
    const float2v t = xc * xc;
    float2v p = t + (float2v){378.f, 378.f};
    p = pfma(p, t, (float2v){17325.f, 17325.f});
    p = pfma(p, t, (float2v){135135.f, 135135.f});
    float2v qq = pfma(t, (float2v){28.f, 28.f}, (float2v){3150.f, 3150.f});
    qq = pfma(qq, t, (float2v){62370.f, 62370.f});
    q  = pfma(qq, t, (float2v){135135.f, 135135.f});
    return xc * p;
}

// One wave = 16 batch elements, private LDS h-region, NO barriers (R4 config —
// measured best). Gates i,f,o weight rows pre-scaled by 0.5
// (sigma(x)=0.5+0.5*tanh(x/2)) so MFMA outputs are tanh args directly.
// Cell math cross-multiplied: 2 scalar rcp per cell, 0 exp.
// C layout: row(batch)=quad*4+reg, col(gate)=lane&15; A: m=lane&15, k=quad*8+j.
__global__ __launch_bounds__(256, 2)
void lstm_mfma_kernel(const float* __restrict__ hist, const float* __restrict__ W_ih,
                      const float* __restrict__ W_hh, const float* __restrict__ b_ih,
                      const float* __restrict__ b_hh, const float* __restrict__ W_pred,
                      const float* __restrict__ b_pred, float* __restrict__ out)
{
    const int lane = threadIdx.x & 63;
    const int wv   = threadIdx.x >> 6;
    const int m    = lane & 15;
    const int quad = lane >> 4;
    const int elem0 = (blockIdx.x * 4 + wv) * 16;

    __shared__ __align__(16) float h_lds_all[4][16][LDS_PAD];
    float (*hl)[LDS_PAD] = h_lds_all[wv];    // per-wave region: no __syncthreads ever

    // ---- resident weight fragments (f16; tiles 0,1=i 2,3=f 4,5=g 6,7=o) ----
    const float gsc[4] = { 0.5f, 0.5f, 1.0f, 0.5f };   // 0.5 for sigma-gates
    half8v Bh[8], B2[8];
    #pragma unroll
    for (int n = 0; n < 8; ++n) {
        const int gc = n * 16 + m;           // gate row 0..127
        const float sc = gsc[n >> 1];
        H8 bh;
        #pragma unroll
        for (int jj = 0; jj < 4; ++jj) {
            bh.h2[jj] = (half2v){ (_Float16)(sc * W_hh[gc * HID + quad * 8 + 2 * jj]),
                                  (_Float16)(sc * W_hh[gc * HID + quad * 8 + 2 * jj + 1]) };
        }
        Bh[n] = bh.h;
        H8 b2; b2.u[0] = b2.u[1] = b2.u[2] = b2.u[3] = 0u;
        if (quad == 0) {
            b2.h2[0] = (half2v){ (_Float16)(sc * W_ih[gc * 4 + 0]), (_Float16)(sc * W_ih[gc * 4 + 1]) };
            b2.h2[1] = (half2v){ (_Float16)(sc * W_ih[gc * 4 + 2]), (_Float16)(sc * W_ih[gc * 4 + 3]) };
            float bsum = sc * (b_ih[gc] + b_hh[gc]);
            _Float16 bhi = (_Float16)bsum;
            _Float16 blo = (_Float16)(bsum - (float)bhi);   // bias exact to ~2^-24
            b2.h2[2] = (half2v){ bhi, blo };                // K rows 4,5 (A = 1,1)
        }
        B2[n] = b2.h;
    }
    const unsigned int one2 = 0x3C003C00u;   // (1.0h, 1.0h)

    // ---- init h = 0 (LDS), c = 0 (regs, paired) ----
    float2v cst[2][2];
    #pragma unroll
    for (int hf = 0; hf < 2; ++hf)
        #pragma unroll
        for (int r = 0; r < 4; ++r) { hl[quad * 4 + r][hf * 16 + m] = 0.f; }
    cst[0][0] = cst[0][1] = cst[1][0] = cst[1][1] = (float2v){0.f, 0.f};
    asm volatile("s_waitcnt lgkmcnt(0)" ::: "memory");

    // ---- encode: 200 steps ----
    const float4* xp = (const float4*)(hist + (size_t)(elem0 + m) * (SEQLEN * 4));
    float4 xv = xp[0];
    #pragma unroll 1
    for (int t = 0; t < SEQLEN; ++t) {
        float4 h0 = *(const float4*)&hl[m][quad * 8];
        float4 h1 = *(const float4*)&hl[m][quad * 8 + 4];
        H8 ahu;
        ahu.u[0] = pk(h0.x, h0.y); ahu.u[1] = pk(h0.z, h0.w);
        ahu.u[2] = pk(h1.x, h1.y); ahu.u[3] = pk(h1.z, h1.w);
        const half8v ah = ahu.h;

        const unsigned int tx0 = pk(xv.x, xv.y), tx1 = pk(xv.z, xv.w);
        H8 a2u;
        a2u.u[0] = (quad == 0) ? tx0 : 0u;
        a2u.u[1] = (quad == 0) ? tx1 : 0u;
        a2u.u[2] = (quad == 0) ? one2 : 0u;
        a2u.u[3] = 0u;
        const half8v a2 = a2u.h;

        const int tn = (t + 1 < SEQLEN) ? t + 1 : SEQLEN - 1;
        float4 xn = xp[tn];                  // prefetch stays in flight

        ACC au[8];
        #pragma unroll
        for (int n = 0; n < 8; ++n) {
            floatx4 a = __builtin_amdgcn_mfma_f32_16x16x32_f16(a2, B2[n], (floatx4){0.f,0.f,0.f,0.f}, 0, 0, 0);
            au[n].f4 = __builtin_amdgcn_mfma_f32_16x16x32_f16(ah, Bh[n], a, 0, 0, 0);
        }
        #pragma unroll
        for (int hf = 0; hf < 2; ++hf) {
            #pragma unroll
            for (int pr = 0; pr < 2; ++pr) {
                float2v gi = au[0 + hf].f2[pr];   // aligned sub-pair: free extract
                float2v gf = au[2 + hf].f2[pr];
                float2v gg = au[4 + hf].f2[pr];
                float2v go = au[6 + hf].f2[pr];
                float2v cc = cst[hf][pr];

                float2v qi, qf, qg;
                float2v ni = tanh_pq(gi, qi);
                float2v nf = tanh_pq(gf, qf);
                float2v ng = tanh_pq(gg, qg);
                // cn = [(qf+nf)*c*qi*qg + (qi+ni)*ng*qf] / (2*qi*qf*qg)
                float2v F   = (qf + nf) * cc * qi;
                float2v C1  = (qi + ni) * ng * qf;
                float2v num = pfma(F, qg, C1);
                float2v den = qi * qf * qg;
                float2v cn  = num * rcp2(den + den);
                // hn = (qo+no)*nc / (2*qo*qc)
                float2v qo, qc;
                float2v no = tanh_pq(go, qo);
                float2v nc = tanh_pq(cn, qc);
                float2v d2 = qo * qc;
                float2v hn = ((qo + no) * nc) * rcp2(d2 + d2);

                cst[hf][pr] = cn;
                hl[quad * 4 + pr * 2][hf * 16 + m]     = hn.x;
                hl[quad * 4 + pr * 2 + 1][hf * 16 + m] = hn.y;
            }
        }
        asm volatile("s_waitcnt lgkmcnt(0)" ::: "memory");  // DS in-order per wave
        xv = xn;
    }

    // ---- decode: 50 steps (c reset to 0 -> f-gate dead; tiles 2,3 skipped) ----
    float wp[4][8];
    #pragma unroll
    for (int d = 0; d < 4; ++d)
        #pragma unroll
        for (int j = 0; j < 8; ++j) wp[d][j] = W_pred[d * HID + quad * 8 + j];
    float bp[4] = { b_pred[0], b_pred[1], b_pred[2], b_pred[3] };

    float* op = out + (size_t)(elem0 + m) * (PSTEPS * 4);
    #pragma unroll 1
    for (int p = 0; p < PSTEPS; ++p) {
        float4 h0 = *(const float4*)&hl[m][quad * 8];
        float4 h1 = *(const float4*)&hl[m][quad * 8 + 4];
        const float hv[8] = { h0.x, h0.y, h0.z, h0.w, h1.x, h1.y, h1.z, h1.w };

        float pd[4];
        #pragma unroll
        for (int d = 0; d < 4; ++d) {
            float s = 0.f;
            #pragma unroll
            for (int j = 0; j < 8; ++j) s = fmaf(hv[j], wp[d][j], s);
            s += __shfl_xor(s, 16);
            s += __shfl_xor(s, 32);
            pd[d] = s + bp[d];
        }
        if (quad == 0) *(float4*)(op + p * 4) = make_float4(pd[0], pd[1], pd[2], pd[3]);

        if (p + 1 < PSTEPS) {
            H8 ahu;
            ahu.u[0] = pk(hv[0], hv[1]); ahu.u[1] = pk(hv[2], hv[3]);
            ahu.u[2] = pk(hv[4], hv[5]); ahu.u[3] = pk(hv[6], hv[7]);
            const half8v ah = ahu.h;
            const unsigned int tx0 = pk(pd[0], pd[1]), tx1 = pk(pd[2], pd[3]);
            H8 a2u;
            a2u.u[0] = (quad == 0) ? tx0 : 0u;
            a2u.u[1] = (quad == 0) ? tx1 : 0u;
            a2u.u[2] = (quad == 0) ? one2 : 0u;
            a2u.u[3] = 0u;
            const half8v a2 = a2u.h;

            ACC au[6];   // tiles 0,1=i ; 4,5=g ; 6,7=o
            #pragma unroll
            for (int nn = 0; nn < 6; ++nn) {
                const int n = (nn < 2) ? nn : nn + 2;
                floatx4 a = __builtin_amdgcn_mfma_f32_16x16x32_f16(a2, B2[n], (floatx4){0.f,0.f,0.f,0.f}, 0, 0, 0);
                au[nn].f4 = __builtin_amdgcn_mfma_f32_16x16x32_f16(ah, Bh[n], a, 0, 0, 0);
            }
            #pragma unroll
            for (int hf = 0; hf < 2; ++hf) {
                #pragma unroll
                for (int pr = 0; pr < 2; ++pr) {
                    float2v gi = au[0 + hf].f2[pr];
                    float2v gg = au[2 + hf].f2[pr];
                    float2v go = au[4 + hf].f2[pr];

                    float2v qi, qg, qo, qc;
                    float2v ni = tanh_pq(gi, qi);
                    float2v ng = tanh_pq(gg, qg);
                    float2v no = tanh_pq(go, qo);
                    // cn = (qi+ni)*ng / (2*qi*qg)   (c == 0)
                    float2v num = (qi + ni) * ng;
                    float2v dg  = qi * qg;
                    float2v cn  = num * rcp2(dg + dg);
                    float2v nc  = tanh_pq(cn, qc);
                    float2v d2  = qo * qc;
                    float2v hn  = ((qo + no) * nc) * rcp2(d2 + d2);

                    hl[quad * 4 + pr * 2][hf * 16 + m]     = hn.x;
                    hl[quad * 4 + pr * 2 + 1][hf * 16 + m] = hn.y;
                }
            }
            asm volatile("s_waitcnt lgkmcnt(0)" ::: "memory");
        }
    }
}

extern "C" void kernel_launch(void* const* d_in, const int* in_sizes, int n_in,
                              void* d_out, int out_size, void* d_ws, size_t ws_size,
                              hipStream_t stream) {
    const float* hist   = (const float*)d_in[0];
    const float* W_ih   = (const float*)d_in[1];
    const float* W_hh   = (const float*)d_in[2];
    const float* b_ih   = (const float*)d_in[3];
    const float* b_hh   = (const float*)d_in[4];
    const float* W_pred = (const float*)d_in[5];
    const float* b_pred = (const float*)d_in[6];
    float* out = (float*)d_out;

    const int blocks = (BATCH / 16) / 4;   // 512 blocks = 2048 waves, 2/SIMD
    lstm_mfma_kernel<<<blocks, 256, 0, stream>>>(hist, W_ih, W_hh, b_ih, b_hh,
                                                 W_pred, b_pred, out);
}

// Round 9
// 410.854 us; speedup vs baseline: 1.3670x; 1.2051x over previous
//
#include <hip/hip_runtime.h>
#include <math.h>

#define BATCH 32768
#define SEQLEN 200
#define PSTEPS 50
#define HID 32
#define LDS_PAD 36   // float row stride 36 -> mild bank aliasing only (m136)

typedef __attribute__((ext_vector_type(2))) _Float16 half2v;
typedef __attribute__((ext_vector_type(8))) _Float16 half8v;
typedef __attribute__((ext_vector_type(2))) __fp16   fp16x2;   // cvt_pkrtz return type
typedef __attribute__((ext_vector_type(4))) float floatx4;

#define EXP2 __builtin_amdgcn_exp2f      // v_exp_f32: 2^x
#define RCPF __builtin_amdgcn_rcpf       // v_rcp_f32
#define PKRTZ __builtin_amdgcn_cvt_pkrtz // v_cvt_pkrtz_f16_f32

#define L1C 1.4426950408889634f          // log2(e)
#define L2C 2.8853900817779268f          // 2*log2(e)

union H8 { unsigned int u[4]; half8v h; half2v h2[4]; };
union HU { fp16x2 h; unsigned int u; };

__device__ __forceinline__ unsigned int pk(float a, float b) {
    HU t; t.h = PKRTZ(a, b); return t.u;
}

// R4 structure (proven best: 338 us rocprof): one wave = 16 batch elements,
// private LDS h-region, NO barriers. NEW vs R4: exp-domain scale constants
// folded into the weights — i/f/o rows x -log2(e), g rows x 2*log2(e) — so
// MFMA outputs are exp2 arguments directly (saves 4 v_mul per cell).
//   sigma(x) = 1/(1+exp2(xs)),  xs = -log2e*x   (ei = exp2(gate))
//   tanh(g)  = (exp2(gs)-1)/(exp2(gs)+1), gs = 2log2e*g
// C layout: row(batch)=quad*4+reg, col(gate)=lane&15; A: m=lane&15, k=quad*8+j.
__global__ __launch_bounds__(256, 2)
void lstm_mfma_kernel(const float* __restrict__ hist, const float* __restrict__ W_ih,
                      const float* __restrict__ W_hh, const float* __restrict__ b_ih,
                      const float* __restrict__ b_hh, const float* __restrict__ W_pred,
                      const float* __restrict__ b_pred, float* __restrict__ out)
{
    const int lane = threadIdx.x & 63;
    const int wv   = threadIdx.x >> 6;
    const int m    = lane & 15;
    const int quad = lane >> 4;
    const int elem0 = (blockIdx.x * 4 + wv) * 16;

    __shared__ __align__(16) float h_lds_all[4][16][LDS_PAD];
    float (*hl)[LDS_PAD] = h_lds_all[wv];    // per-wave region: no __syncthreads ever

    // ---- resident weight fragments (f16, exp-scale folded; tiles 0,1=i 2,3=f 4,5=g 6,7=o) ----
    const float esc[4] = { -L1C, -L1C, L2C, -L1C };   // i,f,g,o exp2-domain scales
    half8v Bh[8], B2[8];
    #pragma unroll
    for (int n = 0; n < 8; ++n) {
        const int gc = n * 16 + m;           // gate row 0..127
        const float sc = esc[n >> 1];
        H8 bh;
        #pragma unroll
        for (int jj = 0; jj < 4; ++jj) {
            bh.h2[jj] = (half2v){ (_Float16)(sc * W_hh[gc * HID + quad * 8 + 2 * jj]),
                                  (_Float16)(sc * W_hh[gc * HID + quad * 8 + 2 * jj + 1]) };
        }
        Bh[n] = bh.h;
        H8 b2; b2.u[0] = b2.u[1] = b2.u[2] = b2.u[3] = 0u;
        if (quad == 0) {
            b2.h2[0] = (half2v){ (_Float16)(sc * W_ih[gc * 4 + 0]), (_Float16)(sc * W_ih[gc * 4 + 1]) };
            b2.h2[1] = (half2v){ (_Float16)(sc * W_ih[gc * 4 + 2]), (_Float16)(sc * W_ih[gc * 4 + 3]) };
            float bsum = sc * (b_ih[gc] + b_hh[gc]);
            _Float16 bhi = (_Float16)bsum;
            _Float16 blo = (_Float16)(bsum - (float)bhi);   // bias exact to ~2^-24
            b2.h2[2] = (half2v){ bhi, blo };                // K rows 4,5 (A = 1,1)
        }
        B2[n] = b2.h;
    }
    const unsigned int one2 = 0x3C003C00u;   // (1.0h, 1.0h)

    // ---- init h = 0 (LDS), c = 0 (regs) ----
    float cst[2][4];
    #pragma unroll
    for (int hf = 0; hf < 2; ++hf)
        #pragma unroll
        for (int r = 0; r < 4; ++r) { cst[hf][r] = 0.f; hl[quad * 4 + r][hf * 16 + m] = 0.f; }
    asm volatile("s_waitcnt lgkmcnt(0)" ::: "memory");

    // ---- encode: 200 steps ----
    const float4* xp = (const float4*)(hist + (size_t)(elem0 + m) * (SEQLEN * 4));
    float4 xv = xp[0];
    #pragma unroll 1
    for (int t = 0; t < SEQLEN; ++t) {
        float4 h0 = *(const float4*)&hl[m][quad * 8];
        float4 h1 = *(const float4*)&hl[m][quad * 8 + 4];
        H8 ahu;
        ahu.u[0] = pk(h0.x, h0.y); ahu.u[1] = pk(h0.z, h0.w);
        ahu.u[2] = pk(h1.x, h1.y); ahu.u[3] = pk(h1.z, h1.w);
        const half8v ah = ahu.h;

        const unsigned int tx0 = pk(xv.x, xv.y), tx1 = pk(xv.z, xv.w);
        H8 a2u;
        a2u.u[0] = (quad == 0) ? tx0 : 0u;
        a2u.u[1] = (quad == 0) ? tx1 : 0u;
        a2u.u[2] = (quad == 0) ? one2 : 0u;
        a2u.u[3] = 0u;
        const half8v a2 = a2u.h;

        const int tn = (t + 1 < SEQLEN) ? t + 1 : SEQLEN - 1;
        float4 xn = xp[tn];                  // prefetch stays in flight

        floatx4 acc[8];
        #pragma unroll
        for (int n = 0; n < 8; ++n) {
            floatx4 a = __builtin_amdgcn_mfma_f32_16x16x32_f16(a2, B2[n], (floatx4){0.f,0.f,0.f,0.f}, 0, 0, 0);
            acc[n] = __builtin_amdgcn_mfma_f32_16x16x32_f16(ah, Bh[n], a, 0, 0, 0);
        }
        // gates arrive in exp2 domain: no per-gate scale muls
        #pragma unroll
        for (int hf = 0; hf < 2; ++hf) {
            #pragma unroll
            for (int r = 0; r < 4; ++r) {
                const float ei = EXP2(acc[0 + hf][r]);
                const float ef = EXP2(acc[2 + hf][r]);
                const float eg = EXP2(acc[4 + hf][r]);
                const float eo = EXP2(acc[6 + hf][r]);
                // cn = c/(1+ef) + (eg-1)/((1+ei)(1+eg)), single shared rcp
                const float pf = 1.0f + ef;
                const float t1 = (1.0f + ei) * (1.0f + eg);
                const float num = fmaf(cst[hf][r], t1, (eg - 1.0f) * pf);
                float cn = num * RCPF(t1 * pf);
                cn = fminf(fmaxf(cn, -30.0f), 30.0f);   // keep exp2(L2C*cn) finite
                const float ec = EXP2(cn * L2C);
                const float hn = (ec - 1.0f) * RCPF((1.0f + eo) * (1.0f + ec));
                cst[hf][r] = cn;
                hl[quad * 4 + r][hf * 16 + m] = hn;
            }
        }
        asm volatile("s_waitcnt lgkmcnt(0)" ::: "memory");  // DS in-order per wave
        xv = xn;
    }

    // ---- decode: 50 steps (c reset to 0 -> f-gate dead; tiles 2,3 skipped) ----
    float wp[4][8];
    #pragma unroll
    for (int d = 0; d < 4; ++d)
        #pragma unroll
        for (int j = 0; j < 8; ++j) wp[d][j] = W_pred[d * HID + quad * 8 + j];
    float bp[4] = { b_pred[0], b_pred[1], b_pred[2], b_pred[3] };

    float* op = out + (size_t)(elem0 + m) * (PSTEPS * 4);
    #pragma unroll 1
    for (int p = 0; p < PSTEPS; ++p) {
        float4 h0 = *(const float4*)&hl[m][quad * 8];
        float4 h1 = *(const float4*)&hl[m][quad * 8 + 4];
        const float hv[8] = { h0.x, h0.y, h0.z, h0.w, h1.x, h1.y, h1.z, h1.w };

        float pd[4];
        #pragma unroll
        for (int d = 0; d < 4; ++d) {
            float s = 0.f;
            #pragma unroll
            for (int j = 0; j < 8; ++j) s = fmaf(hv[j], wp[d][j], s);
            s += __shfl_xor(s, 16);
            s += __shfl_xor(s, 32);
            pd[d] = s + bp[d];
        }
        if (quad == 0) *(float4*)(op + p * 4) = make_float4(pd[0], pd[1], pd[2], pd[3]);

        if (p + 1 < PSTEPS) {
            H8 ahu;
            ahu.u[0] = pk(hv[0], hv[1]); ahu.u[1] = pk(hv[2], hv[3]);
            ahu.u[2] = pk(hv[4], hv[5]); ahu.u[3] = pk(hv[6], hv[7]);
            const half8v ah = ahu.h;
            const unsigned int tx0 = pk(pd[0], pd[1]), tx1 = pk(pd[2], pd[3]);
            H8 a2u;
            a2u.u[0] = (quad == 0) ? tx0 : 0u;
            a2u.u[1] = (quad == 0) ? tx1 : 0u;
            a2u.u[2] = (quad == 0) ? one2 : 0u;
            a2u.u[3] = 0u;
            const half8v a2 = a2u.h;

            floatx4 acc[6];   // tiles 0,1=i ; 4,5=g ; 6,7=o
            #pragma unroll
            for (int nn = 0; nn < 6; ++nn) {
                const int n = (nn < 2) ? nn : nn + 2;
                floatx4 a = __builtin_amdgcn_mfma_f32_16x16x32_f16(a2, B2[n], (floatx4){0.f,0.f,0.f,0.f}, 0, 0, 0);
                acc[nn] = __builtin_amdgcn_mfma_f32_16x16x32_f16(ah, Bh[n], a, 0, 0, 0);
            }
            #pragma unroll
            for (int hf = 0; hf < 2; ++hf) {
                #pragma unroll
                for (int r = 0; r < 4; ++r) {
                    const float ei = EXP2(acc[0 + hf][r]);
                    const float eg = EXP2(acc[2 + hf][r]);
                    const float eo = EXP2(acc[4 + hf][r]);
                    // cn = sigma(i)*tanh(g) = (eg-1)/((1+ei)(1+eg)); |cn|<1
                    const float cn = (eg - 1.0f) * RCPF((1.0f + ei) * (1.0f + eg));
                    const float ec = EXP2(cn * L2C);
                    const float hn = (ec - 1.0f) * RCPF((1.0f + eo) * (1.0f + ec));
                    hl[quad * 4 + r][hf * 16 + m] = hn;
                }
            }
            asm volatile("s_waitcnt lgkmcnt(0)" ::: "memory");
        }
    }
}

extern "C" void kernel_launch(void* const* d_in, const int* in_sizes, int n_in,
                              void* d_out, int out_size, void* d_ws, size_t ws_size,
                              hipStream_t stream) {
    const float* hist   = (const float*)d_in[0];
    const float* W_ih   = (const float*)d_in[1];
    const float* W_hh   = (const float*)d_in[2];
    const float* b_ih   = (const float*)d_in[3];
    const float* b_hh   = (const float*)d_in[4];
    const float* W_pred = (const float*)d_in[5];
    const float* b_pred = (const float*)d_in[6];
    float* out = (float*)d_out;

    const int blocks = (BATCH / 16) / 4;   // 512 blocks = 2048 waves, 2/SIMD
    lstm_mfma_kernel<<<blocks, 256, 0, stream>>>(hist, W_ih, W_hh, b_ih, b_hh,
                                                 W_pred, b_pred, out);
}

// Round 10
// 400.967 us; speedup vs baseline: 1.4007x; 1.0247x over previous
//
#include <hip/hip_runtime.h>
#include <math.h>

#define BATCH 32768
#define SEQLEN 200
#define PSTEPS 50
#define HID 32
#define LDS_PAD 36   // float row stride 36 -> mild bank aliasing only (m136)

typedef __attribute__((ext_vector_type(2))) _Float16 half2v;
typedef __attribute__((ext_vector_type(8))) _Float16 half8v;
typedef __attribute__((ext_vector_type(2))) __fp16   fp16x2;   // cvt_pkrtz return type
typedef __attribute__((ext_vector_type(4))) float floatx4;

#define EXP2 __builtin_amdgcn_exp2f      // v_exp_f32: 2^x
#define RCPF __builtin_amdgcn_rcpf       // v_rcp_f32
#define PKRTZ __builtin_amdgcn_cvt_pkrtz // v_cvt_pkrtz_f16_f32
#define MED3 __builtin_amdgcn_fmed3f     // v_med3_f32

#define L1C 1.4426950408889634f          // log2(e)
#define L2C 2.8853900817779268f          // 2*log2(e)

union H8 { unsigned int u[4]; half8v h; half2v h2[4]; };
union HU { fp16x2 h; unsigned int u; };

__device__ __forceinline__ unsigned int pk(float a, float b) {
    HU t; t.h = PKRTZ(a, b); return t.u;
}

// R9 structure (one wave = 16 batch elements, private LDS h-region, no
// barriers, exp-domain scales folded into weights) + R10 changes:
//  - rcp PAIRED across cell pairs: rcp(Da*Db) + 2 muls replaces 2 rcps
//  - tanh(c) input clamped to +-12 via med3 (EXACT: tanh(12) == 1.0f in
//    fp32, and (ec-1)*rcp(..(1+ec)) yields exactly 1.0 for any cn >= 12);
//    keeps paired hn-denominator product <= 2^96 (no overflow). State c
//    itself is UNCLAMPED now — matches the JAX ref exactly.
//  - anti-phase stagger: odd co-resident block sleeps ~768 cyc at start so
//    the 2 waves/SIMD hit latency-stall windows out of phase.
// C layout: row(batch)=quad*4+reg, col(gate)=lane&15; A: m=lane&15, k=quad*8+j.
__global__ __launch_bounds__(256, 2)
void lstm_mfma_kernel(const float* __restrict__ hist, const float* __restrict__ W_ih,
                      const float* __restrict__ W_hh, const float* __restrict__ b_ih,
                      const float* __restrict__ b_hh, const float* __restrict__ W_pred,
                      const float* __restrict__ b_pred, float* __restrict__ out)
{
    const int lane = threadIdx.x & 63;
    const int wv   = threadIdx.x >> 6;
    const int m    = lane & 15;
    const int quad = lane >> 4;
    const int elem0 = (blockIdx.x * 4 + wv) * 16;

    // anti-phase: co-resident pair assumed (k, k+256) for 512-block grid
    if ((blockIdx.x >> 8) & 1) __builtin_amdgcn_s_sleep(12);

    __shared__ __align__(16) float h_lds_all[4][16][LDS_PAD];
    float (*hl)[LDS_PAD] = h_lds_all[wv];    // per-wave region: no __syncthreads ever

    // ---- resident weight fragments (f16, exp-scale folded; tiles 0,1=i 2,3=f 4,5=g 6,7=o) ----
    const float esc[4] = { -L1C, -L1C, L2C, -L1C };   // i,f,g,o exp2-domain scales
    half8v Bh[8], B2[8];
    #pragma unroll
    for (int n = 0; n < 8; ++n) {
        const int gc = n * 16 + m;           // gate row 0..127
        const float sc = esc[n >> 1];
        H8 bh;
        #pragma unroll
        for (int jj = 0; jj < 4; ++jj) {
            bh.h2[jj] = (half2v){ (_Float16)(sc * W_hh[gc * HID + quad * 8 + 2 * jj]),
                                  (_Float16)(sc * W_hh[gc * HID + quad * 8 + 2 * jj + 1]) };
        }
        Bh[n] = bh.h;
        H8 b2; b2.u[0] = b2.u[1] = b2.u[2] = b2.u[3] = 0u;
        if (quad == 0) {
            b2.h2[0] = (half2v){ (_Float16)(sc * W_ih[gc * 4 + 0]), (_Float16)(sc * W_ih[gc * 4 + 1]) };
            b2.h2[1] = (half2v){ (_Float16)(sc * W_ih[gc * 4 + 2]), (_Float16)(sc * W_ih[gc * 4 + 3]) };
            float bsum = sc * (b_ih[gc] + b_hh[gc]);
            _Float16 bhi = (_Float16)bsum;
            _Float16 blo = (_Float16)(bsum - (float)bhi);   // bias exact to ~2^-24
            b2.h2[2] = (half2v){ bhi, blo };                // K rows 4,5 (A = 1,1)
        }
        B2[n] = b2.h;
    }
    const unsigned int one2 = 0x3C003C00u;   // (1.0h, 1.0h)

    // ---- init h = 0 (LDS), c = 0 (regs) ----
    float cst[2][4];
    #pragma unroll
    for (int hf = 0; hf < 2; ++hf)
        #pragma unroll
        for (int r = 0; r < 4; ++r) { cst[hf][r] = 0.f; hl[quad * 4 + r][hf * 16 + m] = 0.f; }
    asm volatile("s_waitcnt lgkmcnt(0)" ::: "memory");

    // ---- encode: 200 steps ----
    const float4* xp = (const float4*)(hist + (size_t)(elem0 + m) * (SEQLEN * 4));
    float4 xv = xp[0];
    #pragma unroll 1
    for (int t = 0; t < SEQLEN; ++t) {
        float4 h0 = *(const float4*)&hl[m][quad * 8];
        float4 h1 = *(const float4*)&hl[m][quad * 8 + 4];
        H8 ahu;
        ahu.u[0] = pk(h0.x, h0.y); ahu.u[1] = pk(h0.z, h0.w);
        ahu.u[2] = pk(h1.x, h1.y); ahu.u[3] = pk(h1.z, h1.w);
        const half8v ah = ahu.h;

        const unsigned int tx0 = pk(xv.x, xv.y), tx1 = pk(xv.z, xv.w);
        H8 a2u;
        a2u.u[0] = (quad == 0) ? tx0 : 0u;
        a2u.u[1] = (quad == 0) ? tx1 : 0u;
        a2u.u[2] = (quad == 0) ? one2 : 0u;
        a2u.u[3] = 0u;
        const half8v a2 = a2u.h;

        const int tn = (t + 1 < SEQLEN) ? t + 1 : SEQLEN - 1;
        float4 xn = xp[tn];                  // prefetch stays in flight

        floatx4 acc[8];
        #pragma unroll
        for (int n = 0; n < 8; ++n) {
            floatx4 a = __builtin_amdgcn_mfma_f32_16x16x32_f16(a2, B2[n], (floatx4){0.f,0.f,0.f,0.f}, 0, 0, 0);
            acc[n] = __builtin_amdgcn_mfma_f32_16x16x32_f16(ah, Bh[n], a, 0, 0, 0);
        }
        // gates arrive in exp2 domain; cells processed in pairs (shared rcps)
        #pragma unroll
        for (int hf = 0; hf < 2; ++hf) {
            #pragma unroll
            for (int pr = 0; pr < 2; ++pr) {
                const int r0 = pr * 2, r1 = r0 + 1;
                const float eiA = EXP2(acc[0 + hf][r0]), eiB = EXP2(acc[0 + hf][r1]);
                const float efA = EXP2(acc[2 + hf][r0]), efB = EXP2(acc[2 + hf][r1]);
                const float egA = EXP2(acc[4 + hf][r0]), egB = EXP2(acc[4 + hf][r1]);
                const float eoA = EXP2(acc[6 + hf][r0]), eoB = EXP2(acc[6 + hf][r1]);
                // cn = c/(1+ef) + (eg-1)/((1+ei)(1+eg)) ; rcp shared across pair
                const float pfA = 1.f + efA,                  pfB = 1.f + efB;
                const float t1A = (1.f + eiA) * (1.f + egA),  t1B = (1.f + eiB) * (1.f + egB);
                const float numA = fmaf(cst[hf][r0], t1A, (egA - 1.f) * pfA);
                const float numB = fmaf(cst[hf][r1], t1B, (egB - 1.f) * pfB);
                const float dA = t1A * pfA, dB = t1B * pfB;   // <= 2^52 each
                const float R  = RCPF(dA * dB);               // <= 2^104: safe
                const float cnA = numA * (R * dB);
                const float cnB = numB * (R * dA);
                // tanh input clamp +-12: EXACT (tanh(12)==1.0f in fp32) and
                // bounds ec <= 2^34.6 so the paired denom <= 2^96
                const float ecA = EXP2(MED3(cnA, -12.f, 12.f) * L2C);
                const float ecB = EXP2(MED3(cnB, -12.f, 12.f) * L2C);
                const float dhA = (1.f + eoA) * (1.f + ecA);
                const float dhB = (1.f + eoB) * (1.f + ecB);
                const float Rh  = RCPF(dhA * dhB);
                const float hnA = (ecA - 1.f) * (Rh * dhB);
                const float hnB = (ecB - 1.f) * (Rh * dhA);

                cst[hf][r0] = cnA; cst[hf][r1] = cnB;         // state UNclamped (matches ref)
                hl[quad * 4 + r0][hf * 16 + m] = hnA;
                hl[quad * 4 + r1][hf * 16 + m] = hnB;
            }
        }
        asm volatile("s_waitcnt lgkmcnt(0)" ::: "memory");  // DS in-order per wave
        xv = xn;
    }

    // ---- decode: 50 steps (c reset to 0 -> f-gate dead; tiles 2,3 skipped) ----
    float wp[4][8];
    #pragma unroll
    for (int d = 0; d < 4; ++d)
        #pragma unroll
        for (int j = 0; j < 8; ++j) wp[d][j] = W_pred[d * HID + quad * 8 + j];
    float bp[4] = { b_pred[0], b_pred[1], b_pred[2], b_pred[3] };

    float* op = out + (size_t)(elem0 + m) * (PSTEPS * 4);
    #pragma unroll 1
    for (int p = 0; p < PSTEPS; ++p) {
        float4 h0 = *(const float4*)&hl[m][quad * 8];
        float4 h1 = *(const float4*)&hl[m][quad * 8 + 4];
        const float hv[8] = { h0.x, h0.y, h0.z, h0.w, h1.x, h1.y, h1.z, h1.w };

        float pd[4];
        #pragma unroll
        for (int d = 0; d < 4; ++d) {
            float s = 0.f;
            #pragma unroll
            for (int j = 0; j < 8; ++j) s = fmaf(hv[j], wp[d][j], s);
            s += __shfl_xor(s, 16);
            s += __shfl_xor(s, 32);
            pd[d] = s + bp[d];
        }
        if (quad == 0) *(float4*)(op + p * 4) = make_float4(pd[0], pd[1], pd[2], pd[3]);

        if (p + 1 < PSTEPS) {
            H8 ahu;
            ahu.u[0] = pk(hv[0], hv[1]); ahu.u[1] = pk(hv[2], hv[3]);
            ahu.u[2] = pk(hv[4], hv[5]); ahu.u[3] = pk(hv[6], hv[7]);
            const half8v ah = ahu.h;
            const unsigned int tx0 = pk(pd[0], pd[1]), tx1 = pk(pd[2], pd[3]);
            H8 a2u;
            a2u.u[0] = (quad == 0) ? tx0 : 0u;
            a2u.u[1] = (quad == 0) ? tx1 : 0u;
            a2u.u[2] = (quad == 0) ? one2 : 0u;
            a2u.u[3] = 0u;
            const half8v a2 = a2u.h;

            floatx4 acc[6];   // tiles 0,1=i ; 4,5=g ; 6,7=o
            #pragma unroll
            for (int nn = 0; nn < 6; ++nn) {
                const int n = (nn < 2) ? nn : nn + 2;
                floatx4 a = __builtin_amdgcn_mfma_f32_16x16x32_f16(a2, B2[n], (floatx4){0.f,0.f,0.f,0.f}, 0, 0, 0);
                acc[nn] = __builtin_amdgcn_mfma_f32_16x16x32_f16(ah, Bh[n], a, 0, 0, 0);
            }
            #pragma unroll
            for (int hf = 0; hf < 2; ++hf) {
                #pragma unroll
                for (int pr = 0; pr < 2; ++pr) {
                    const int r0 = pr * 2, r1 = r0 + 1;
                    const float eiA = EXP2(acc[0 + hf][r0]), eiB = EXP2(acc[0 + hf][r1]);
                    const float egA = EXP2(acc[2 + hf][r0]), egB = EXP2(acc[2 + hf][r1]);
                    const float eoA = EXP2(acc[4 + hf][r0]), eoB = EXP2(acc[4 + hf][r1]);
                    // cn = (eg-1)/((1+ei)(1+eg)) (c==0); |cn|<1
                    const float dA = (1.f + eiA) * (1.f + egA);
                    const float dB = (1.f + eiB) * (1.f + egB);
                    const float R  = RCPF(dA * dB);
                    const float cnA = (egA - 1.f) * (R * dB);
                    const float cnB = (egB - 1.f) * (R * dA);
                    const float ecA = EXP2(cnA * L2C);        // ec in [2^-2.9, 2^2.9]
                    const float ecB = EXP2(cnB * L2C);
                    const float dhA = (1.f + eoA) * (1.f + ecA);
                    const float dhB = (1.f + eoB) * (1.f + ecB);
                    const float Rh  = RCPF(dhA * dhB);
                    const float hnA = (ecA - 1.f) * (Rh * dhB);
                    const float hnB = (ecB - 1.f) * (Rh * dhA);

                    hl[quad * 4 + r0][hf * 16 + m] = hnA;
                    hl[quad * 4 + r1][hf * 16 + m] = hnB;
                }
            }
            asm volatile("s_waitcnt lgkmcnt(0)" ::: "memory");
        }
    }
}

extern "C" void kernel_launch(void* const* d_in, const int* in_sizes, int n_in,
                              void* d_out, int out_size, void* d_ws, size_t ws_size,
                              hipStream_t stream) {
    const float* hist   = (const float*)d_in[0];
    const float* W_ih   = (const float*)d_in[1];
    const float* W_hh   = (const float*)d_in[2];
    const float* b_ih   = (const float*)d_in[3];
    const float* b_hh   = (const float*)d_in[4];
    const float* W_pred = (const float*)d_in[5];
    const float* b_pred = (const float*)d_in[6];
    float* out = (float*)d_out;

    const int blocks = (BATCH / 16) / 4;   // 512 blocks = 2048 waves, 2/SIMD
    lstm_mfma_kernel<<<blocks, 256, 0, stream>>>(hist, W_ih, W_hh, b_ih, b_hh,
                                                 W_pred, b_pred, out);
}